// Round 2
// baseline (398.580 us; speedup 1.0000x reference)
//
#include <hip/hip_runtime.h>

// SSIM3D loss, fused separable 11^3 Gaussian conv of 5 fields + SSIM map + mean.
// Round 2: D-chunking (DC=32, grid 1024 blocks -> 2 blocks/CU resident via
// __launch_bounds__(512,4)), hoisted 32-bit staging addresses, slim LDS.

#define DD 128
#define HH 256
#define WW 256
#define TH 32
#define TW 16
#define DC 32              // D outputs per block
#define KS 11
#define HALO 5
#define XH 42              // TH + 10
#define XW 26              // TW + 10
#define XSTR 28            // padded LDS row stride (floats)
#define WBSTR 17           // wb row stride (floats)
#define WBPL (XH * WBSTR)  // 714 floats per field plane
#define NTH 512
#define NPTS (XH * XW)     // 1092 staging points
#define PLANE 65536        // 256*256
#define C1F 1.0e-4f
#define C2F 9.0e-4f
#define NVOX (2.0 * 128.0 * 256.0 * 256.0)

// init: zero accumulator, extract separable g[11] (row sums of the 11^3 window)
__global__ void ssim_init_kernel(const float* __restrict__ win,
                                 double* __restrict__ acc,
                                 float* __restrict__ g) {
    int i = threadIdx.x;
    if (i == 0) acc[0] = 0.0;
    if (i < KS) {
        float s = 0.f;
        #pragma unroll 1
        for (int j = 0; j < KS * KS; ++j) s += win[i * KS * KS + j];
        g[i] = s;
    }
}

__global__ __launch_bounds__(NTH, 4)
void ssim_main_kernel(const float* __restrict__ img1,
                      const float* __restrict__ img2,
                      const float* __restrict__ gcoef,
                      double* __restrict__ acc) {
    __shared__ float xt[XH * XSTR];
    __shared__ float yt[XH * XSTR];
    __shared__ float wb[5 * WBPL];
    __shared__ double red[NTH / 64];

    const int tid = threadIdx.x;
    const int tx = tid & 15;
    const int ty = tid >> 4;              // 0..31
    const int w0 = blockIdx.x * TW;
    const int h0 = blockIdx.y * TH;
    const int b  = blockIdx.z >> 2;       // batch
    const int d0 = (blockIdx.z & 3) * DC; // chunk start in D

    const float* base1 = img1 + (size_t)b * (DD * PLANE);
    const float* base2 = img2 + (size_t)b * (DD * PLANE);

    // --- hoisted staging geometry: 3 segments of 512 covering 1092 points ---
    int   goff[3];   // 32-bit global in-plane offset (clamped)
    int   loff[3];   // LDS offset (floats)
    float mskf[3];   // 0 for out-of-plane halo lanes
    #pragma unroll
    for (int sg = 0; sg < 3; ++sg) {
        int p = tid + sg * NTH;
        int r = p / XW;
        int c = p - r * XW;
        int gh = h0 - HALO + r;
        int gw = w0 - HALO + c;
        bool v = (p < NPTS) && ((unsigned)gh < HH) && ((unsigned)gw < WW);
        goff[sg] = v ? (gh * WW + gw) : 0;
        mskf[sg] = v ? 1.f : 0.f;
        loff[sg] = r * XSTR + c;
    }

    float G[KS];
    #pragma unroll
    for (int i = 0; i < KS; ++i) G[i] = gcoef[i];

    float ring[5][KS];
    #pragma unroll
    for (int f = 0; f < 5; ++f)
        #pragma unroll
        for (int i = 0; i < KS; ++i) ring[f][i] = 0.f;

    // --- prefetch slice s=0 (dIn = d0-5) ---
    float pv1[3], pv2[3];
    {
        int dIn = d0 - HALO;
        if ((unsigned)dIn < DD) {
            const float* s1 = base1 + dIn * PLANE;
            const float* s2 = base2 + dIn * PLANE;
            #pragma unroll
            for (int sg = 0; sg < 3; ++sg) {
                pv1[sg] = s1[goff[sg]];
                pv2[sg] = s2[goff[sg]];
            }
        } else {
            #pragma unroll
            for (int sg = 0; sg < 3; ++sg) { pv1[sg] = 0.f; pv2[sg] = 0.f; }
        }
    }

    double lsum = 0.0;

    for (int s = 0; s < DC + 2 * HALO; ++s) {
        // shift D-ring (statically indexed)
        #pragma unroll
        for (int f = 0; f < 5; ++f)
            #pragma unroll
            for (int i = 0; i < KS - 1; ++i) ring[f][i] = ring[f][i + 1];

        // commit prefetched slice to LDS (halo lanes zeroed by mask)
        #pragma unroll
        for (int sg = 0; sg < 3; ++sg) {
            int p = tid + sg * NTH;
            if (p < NPTS) {
                xt[loff[sg]] = pv1[sg] * mskf[sg];
                yt[loff[sg]] = pv2[sg] * mskf[sg];
            }
        }
        __syncthreads();

        // issue prefetch for next slice; lands under W/H-conv
        {
            int dIn = d0 - HALO + s + 1;
            if ((s + 1 < DC + 2 * HALO) && ((unsigned)dIn < DD)) {
                const float* s1 = base1 + dIn * PLANE;
                const float* s2 = base2 + dIn * PLANE;
                #pragma unroll
                for (int sg = 0; sg < 3; ++sg) {
                    pv1[sg] = s1[goff[sg]];
                    pv2[sg] = s2[goff[sg]];
                }
            } else {
                #pragma unroll
                for (int sg = 0; sg < 3; ++sg) { pv1[sg] = 0.f; pv2[sg] = 0.f; }
            }
        }

        // W-conv segment A: rows 0..31 (all 512 threads)
        {
            const float* xrow = &xt[ty * XSTR + tx];
            const float* yrow = &yt[ty * XSTR + tx];
            float a0 = 0.f, a1 = 0.f, a2 = 0.f, a3 = 0.f, a4 = 0.f;
            #pragma unroll
            for (int k = 0; k < KS; ++k) {
                float xv = xrow[k], yv = yrow[k], gk = G[k];
                float txv = gk * xv, tyv = gk * yv;
                a0 += txv; a1 += tyv;
                a2 += txv * xv; a3 += tyv * yv; a4 += txv * yv;
            }
            int o = ty * WBSTR + tx;
            wb[o] = a0; wb[WBPL + o] = a1; wb[2 * WBPL + o] = a2;
            wb[3 * WBPL + o] = a3; wb[4 * WBPL + o] = a4;
        }
        // W-conv segment B: rows 32..41 (first 160 threads)
        if (tid < (XH * TW - NTH)) {
            int r = TH + ty;   // 32..41
            const float* xrow = &xt[r * XSTR + tx];
            const float* yrow = &yt[r * XSTR + tx];
            float a0 = 0.f, a1 = 0.f, a2 = 0.f, a3 = 0.f, a4 = 0.f;
            #pragma unroll
            for (int k = 0; k < KS; ++k) {
                float xv = xrow[k], yv = yrow[k], gk = G[k];
                float txv = gk * xv, tyv = gk * yv;
                a0 += txv; a1 += tyv;
                a2 += txv * xv; a3 += tyv * yv; a4 += txv * yv;
            }
            int o = r * WBSTR + tx;
            wb[o] = a0; wb[WBPL + o] = a1; wb[2 * WBPL + o] = a2;
            wb[3 * WBPL + o] = a3; wb[4 * WBPL + o] = a4;
        }
        __syncthreads();

        // H-conv: one output per thread
        float s0 = 0.f, s1 = 0.f, s2 = 0.f, s3 = 0.f, s4 = 0.f;
        #pragma unroll
        for (int k = 0; k < KS; ++k) {
            int o = (ty + k) * WBSTR + tx;
            float gk = G[k];
            s0 += gk * wb[o];
            s1 += gk * wb[WBPL + o];
            s2 += gk * wb[2 * WBPL + o];
            s3 += gk * wb[3 * WBPL + o];
            s4 += gk * wb[4 * WBPL + o];
        }
        ring[0][KS-1] = s0; ring[1][KS-1] = s1; ring[2][KS-1] = s2;
        ring[3][KS-1] = s3; ring[4][KS-1] = s4;

        // emit output slice d0 + s - 10 (always in range once warm)
        if (s >= 2 * HALO) {
            float m1 = 0.f, m2 = 0.f, exx = 0.f, eyy = 0.f, exy = 0.f;
            #pragma unroll
            for (int i = 0; i < KS; ++i) {
                float gi = G[i];
                m1  += gi * ring[0][i];
                m2  += gi * ring[1][i];
                exx += gi * ring[2][i];
                eyy += gi * ring[3][i];
                exy += gi * ring[4][i];
            }
            float mu11 = m1 * m1, mu22 = m2 * m2, mu12 = m1 * m2;
            float sg1  = exx - mu11;
            float sg2  = eyy - mu22;
            float sg12 = exy - mu12;
            float num = (2.f * mu12 + C1F) * (2.f * sg12 + C2F);
            float den = (mu11 + mu22 + C1F) * (sg1 + sg2 + C2F);
            lsum += (double)(num / den);
        }
    }

    // block reduction -> one f64 atomic
    #pragma unroll
    for (int off = 32; off > 0; off >>= 1)
        lsum += __shfl_down(lsum, off, 64);
    int lane = tid & 63, wid = tid >> 6;
    if (lane == 0) red[wid] = lsum;
    __syncthreads();
    if (tid == 0) {
        double bsum = 0.0;
        #pragma unroll
        for (int wv = 0; wv < NTH / 64; ++wv) bsum += red[wv];
        atomicAdd(acc, bsum);
    }
}

__global__ void ssim_fin_kernel(const double* __restrict__ acc,
                                float* __restrict__ out) {
    out[0] = (float)(1.0 - acc[0] / NVOX);
}

extern "C" void kernel_launch(void* const* d_in, const int* in_sizes, int n_in,
                              void* d_out, int out_size, void* d_ws, size_t ws_size,
                              hipStream_t stream) {
    const float* img1 = (const float*)d_in[0];
    const float* img2 = (const float*)d_in[1];
    const float* win  = (const float*)d_in[2];
    double* acc = (double*)d_ws;
    float*  g   = (float*)((char*)d_ws + 16);

    hipLaunchKernelGGL(ssim_init_kernel, dim3(1), dim3(64), 0, stream, win, acc, g);
    hipLaunchKernelGGL(ssim_main_kernel, dim3(WW / TW, HH / TH, 2 * (DD / DC)),
                       dim3(NTH), 0, stream, img1, img2, g, acc);
    hipLaunchKernelGGL(ssim_fin_kernel, dim3(1), dim3(1), 0, stream, acc, (float*)d_out);
}